// Round 6
// baseline (526.506 us; speedup 1.0000x reference)
//
#include <hip/hip_runtime.h>
#include <hip/hip_bf16.h>

#define N_NODES 50000
#define N_EDGES 800000
#define N_GRAPHS 512
#define EMB 64
#define HID 128

// ---------------- embed gather + degree histogram + weight transpose (fused)
// N_NODES*16 == N_EDGES == 800000 threads; first 49152 also transpose weights.
__global__ void k_embed_hist(const int* __restrict__ x, const float* __restrict__ emb,
                             const int* __restrict__ ei, float* __restrict__ h0,
                             int* __restrict__ deg,
                             const float* __restrict__ w1r, const float* __restrict__ w1l,
                             const float* __restrict__ w2r, const float* __restrict__ w2l,
                             float* __restrict__ wt1r, float* __restrict__ wt1l,
                             float* __restrict__ wt2r, float* __restrict__ wt2l) {
    int t = blockIdx.x * 256 + threadIdx.x;
    if (t >= N_EDGES) return;
    int n = t >> 4, c4 = t & 15;
    const float4* e4 = (const float4*)emb;
    ((float4*)h0)[(size_t)n * 16 + c4] = e4[(size_t)x[n] * 16 + c4];
    atomicAdd(&deg[ei[N_EDGES + t]], 1);
    // weight transposes: wt[j][k] = w[k][j]
    if (t < 8192) {            // w1_r: 64x128 -> 128x64
        int j = t & 127, k = t >> 7;
        wt1r[j * 64 + k] = w1r[k * 128 + j];
    } else if (t < 16384) {    // w1_l
        int u = t - 8192; int j = u & 127, k = u >> 7;
        wt1l[j * 64 + k] = w1l[k * 128 + j];
    } else if (t < 32768) {    // w2_r: 128x128
        int u = t - 16384; int j = u & 127, k = u >> 7;
        wt2r[j * 128 + k] = w2r[k * 128 + j];
    } else if (t < 49152) {    // w2_l
        int u = t - 32768; int j = u & 127, k = u >> 7;
        wt2l[j * 128 + k] = w2l[k * 128 + j];
    }
}

// ---------------------------------------------------------------- 3-phase scan
__global__ void k_scanA(const int* __restrict__ deg, int* __restrict__ rowptr,
                        int* __restrict__ bsums) {
    __shared__ int s[256];
    int t = threadIdx.x, i = blockIdx.x * 256 + t;
    int v = (i < N_NODES) ? deg[i] : 0;
    s[t] = v; __syncthreads();
    int xv = v;
    for (int off = 1; off < 256; off <<= 1) {
        int y = (t >= off) ? s[t - off] : 0;
        __syncthreads();
        xv += y; s[t] = xv;
        __syncthreads();
    }
    if (i < N_NODES) rowptr[i] = xv - v;
    if (t == 255) bsums[blockIdx.x] = xv;
}

__global__ void k_scanB(int* __restrict__ bsums, int nb) {
    __shared__ int s[256];
    int t = threadIdx.x;
    int v = (t < nb) ? bsums[t] : 0;
    s[t] = v; __syncthreads();
    int xv = v;
    for (int off = 1; off < 256; off <<= 1) {
        int y = (t >= off) ? s[t - off] : 0;
        __syncthreads();
        xv += y; s[t] = xv;
        __syncthreads();
    }
    if (t < nb) bsums[t] = xv - v;
}

__global__ void k_scanC(int* __restrict__ rowptr, int* __restrict__ wp,
                        const int* __restrict__ bsums) {
    int i = blockIdx.x * 256 + threadIdx.x;
    if (i < N_NODES) {
        int v = rowptr[i] + bsums[blockIdx.x];
        rowptr[i] = v;
        wp[i] = v;
    }
    if (i == 0) rowptr[N_NODES] = N_EDGES;
}

// ---------------------------------------------------------------- edge scatter
__global__ void k_scatter(const int* __restrict__ ei, int* __restrict__ wp,
                          int* __restrict__ nbr) {
    int e = blockIdx.x * 256 + threadIdx.x;
    if (e >= N_EDGES) return;
    int s = ei[e], d = ei[N_EDGES + e];
    int pos = atomicAdd(&wp[d], 1);
    nbr[pos] = s;
}

// ---------------------------------------------------------------- aggregation
// F=128 -> 2 nodes/wave (32 lanes x float4); F=64 -> 4 nodes/wave.
// 8 independent float4 accumulators -> 8 row loads in flight per node group.
template <int F>
__global__ __launch_bounds__(256) void k_agg(const float* __restrict__ h,
                                             const int* __restrict__ rowptr,
                                             const int* __restrict__ nbr,
                                             float* __restrict__ mean) {
    int w = (blockIdx.x * 256 + threadIdx.x) >> 6;
    int l = threadIdx.x & 63;
    const float4* h4 = (const float4*)h;
    float4* m4 = (float4*)mean;

    int n, c;
    if constexpr (F == 128) { n = w * 2 + (l >> 5); c = l & 31; }
    else                    { n = w * 4 + (l >> 4); c = l & 15; }
    if (n >= N_NODES) return;
    constexpr int C = F / 4;

    int r0 = rowptr[n], r1 = rowptr[n + 1];
    float inv = 1.0f / (float)max(r1 - r0, 1);

    float4 a[8];
    #pragma unroll
    for (int u = 0; u < 8; ++u) a[u] = make_float4(0.f, 0.f, 0.f, 0.f);

    int i = r0;
    for (; i + 7 < r1; i += 8) {
        int s0 = nbr[i + 0], s1 = nbr[i + 1], s2 = nbr[i + 2], s3 = nbr[i + 3];
        int s4 = nbr[i + 4], s5 = nbr[i + 5], s6 = nbr[i + 6], s7 = nbr[i + 7];
        float4 v0 = h4[(size_t)s0 * C + c];
        float4 v1 = h4[(size_t)s1 * C + c];
        float4 v2 = h4[(size_t)s2 * C + c];
        float4 v3 = h4[(size_t)s3 * C + c];
        float4 v4 = h4[(size_t)s4 * C + c];
        float4 v5 = h4[(size_t)s5 * C + c];
        float4 v6 = h4[(size_t)s6 * C + c];
        float4 v7 = h4[(size_t)s7 * C + c];
        a[0].x += v0.x; a[0].y += v0.y; a[0].z += v0.z; a[0].w += v0.w;
        a[1].x += v1.x; a[1].y += v1.y; a[1].z += v1.z; a[1].w += v1.w;
        a[2].x += v2.x; a[2].y += v2.y; a[2].z += v2.z; a[2].w += v2.w;
        a[3].x += v3.x; a[3].y += v3.y; a[3].z += v3.z; a[3].w += v3.w;
        a[4].x += v4.x; a[4].y += v4.y; a[4].z += v4.z; a[4].w += v4.w;
        a[5].x += v5.x; a[5].y += v5.y; a[5].z += v5.z; a[5].w += v5.w;
        a[6].x += v6.x; a[6].y += v6.y; a[6].z += v6.z; a[6].w += v6.w;
        a[7].x += v7.x; a[7].y += v7.y; a[7].z += v7.z; a[7].w += v7.w;
    }
    for (; i + 3 < r1; i += 4) {
        int s0 = nbr[i + 0], s1 = nbr[i + 1], s2 = nbr[i + 2], s3 = nbr[i + 3];
        float4 v0 = h4[(size_t)s0 * C + c];
        float4 v1 = h4[(size_t)s1 * C + c];
        float4 v2 = h4[(size_t)s2 * C + c];
        float4 v3 = h4[(size_t)s3 * C + c];
        a[0].x += v0.x; a[0].y += v0.y; a[0].z += v0.z; a[0].w += v0.w;
        a[1].x += v1.x; a[1].y += v1.y; a[1].z += v1.z; a[1].w += v1.w;
        a[2].x += v2.x; a[2].y += v2.y; a[2].z += v2.z; a[2].w += v2.w;
        a[3].x += v3.x; a[3].y += v3.y; a[3].z += v3.z; a[3].w += v3.w;
    }
    for (; i < r1; ++i) {
        float4 v = h4[(size_t)nbr[i] * C + c];
        a[0].x += v.x; a[0].y += v.y; a[0].z += v.z; a[0].w += v.w;
    }
    #pragma unroll
    for (int u = 1; u < 8; ++u) {
        a[0].x += a[u].x; a[0].y += a[u].y; a[0].z += a[u].z; a[0].w += a[u].w;
    }
    m4[(size_t)n * C + c] = make_float4(a[0].x * inv, a[0].y * inv,
                                        a[0].z * inv, a[0].w * inv);
}

// ---------------------------------------------------------------- layer GEMM
// out = relu(bias + hself@w_r + hmean@w_l) with TRANSPOSED weights wt[j][k]:
// per-column-contiguous scalar streams (s_load_dwordx16), node row held in
// VGPRs in 32-wide chunks loaded直接 from global (L2-hot tile, no LDS).
// block = 512 thr = 8 waves; wave w -> cols [16w,16w+16); lane -> node.
template <int K>
__device__ __forceinline__ void gemm_pass(const float4* __restrict__ src,
                                          const float* __restrict__ wt,
                                          int nclamp, int j0, float (&acc)[16]) {
    const float4* rp = src + (size_t)nclamp * (K / 4);
    for (int kc = 0; kc < K / 32; ++kc) {
        float4 r4[8];
        #pragma unroll
        for (int cc = 0; cc < 8; ++cc) r4[cc] = rp[kc * 8 + cc];
        float row[32];
        #pragma unroll
        for (int cc = 0; cc < 8; ++cc) {
            row[cc * 4 + 0] = r4[cc].x; row[cc * 4 + 1] = r4[cc].y;
            row[cc * 4 + 2] = r4[cc].z; row[cc * 4 + 3] = r4[cc].w;
        }
        #pragma unroll
        for (int j = 0; j < 16; ++j) {
            const float* wr = wt + (size_t)(j0 + j) * K + kc * 32;
            #pragma unroll
            for (int k = 0; k < 32; ++k) acc[j] = fmaf(row[k], wr[k], acc[j]);
        }
    }
}

template <int K>
__global__ __launch_bounds__(512) void k_layer(
    const float* __restrict__ hself, const float* __restrict__ hmean,
    const float* __restrict__ wt_r, const float* __restrict__ wt_l,
    const float* __restrict__ bias, float* __restrict__ out) {
    int t = threadIdx.x;
    int lane = t & 63;
    int wid = __builtin_amdgcn_readfirstlane(t >> 6);   // 0..7
    int j0 = wid * 16;
    int node = blockIdx.x * 64 + lane;
    bool valid = node < N_NODES;
    int nclamp = valid ? node : N_NODES - 1;

    float acc[16];
    #pragma unroll
    for (int j = 0; j < 16; j++) acc[j] = bias[j0 + j];

    gemm_pass<K>((const float4*)hself, wt_r, nclamp, j0, acc);
    gemm_pass<K>((const float4*)hmean, wt_l, nclamp, j0, acc);

    if (!valid) return;
    float4* o4 = (float4*)out;
    #pragma unroll
    for (int jj = 0; jj < 4; jj++) {
        float4 v;
        v.x = fmaxf(acc[jj * 4 + 0], 0.f);
        v.y = fmaxf(acc[jj * 4 + 1], 0.f);
        v.z = fmaxf(acc[jj * 4 + 2], 0.f);
        v.w = fmaxf(acc[jj * 4 + 3], 0.f);
        o4[(size_t)node * 32 + wid * 4 + jj] = v;
    }
}

// ---------------------------------------------------------------- pool + head
__global__ void k_pool_head(const float* __restrict__ h2, const int* __restrict__ batch,
                            const float* __restrict__ w_out, const float* __restrict__ b_out,
                            float* __restrict__ out) {
    int g = blockIdx.x;
    int lo = 0, hi = N_NODES;
    while (lo < hi) { int mid = (lo + hi) >> 1; if (batch[mid] < g) lo = mid + 1; else hi = mid; }
    int s = lo;
    lo = s; hi = N_NODES;
    while (lo < hi) { int mid = (lo + hi) >> 1; if (batch[mid] < g + 1) lo = mid + 1; else hi = mid; }
    int e = lo;

    int f = threadIdx.x & 127, half = threadIdx.x >> 7;
    float acc = 0.0f;
    for (int r = s + half; r < e; r += 2) acc += h2[(size_t)r * 128 + f];
    __shared__ float tmp[256];
    tmp[threadIdx.x] = acc;
    __syncthreads();
    if (half == 0) {
        float p = (tmp[f] + tmp[f + 128]) / (float)max(e - s, 1);
        tmp[f]       = p * w_out[f * 2 + 0];
        tmp[f + 128] = p * w_out[f * 2 + 1];
    }
    __syncthreads();
    for (int str = 64; str > 0; str >>= 1) {
        if (threadIdx.x < str) {
            tmp[threadIdx.x] += tmp[threadIdx.x + str];
            tmp[threadIdx.x + 128] += tmp[threadIdx.x + 128 + str];
        }
        __syncthreads();
    }
    if (threadIdx.x == 0) {
        out[(size_t)g * 2 + 0] = tmp[0] + b_out[0];
        out[(size_t)g * 2 + 1] = tmp[128] + b_out[1];
    }
}

// ---------------------------------------------------------------- launch
extern "C" void kernel_launch(void* const* d_in, const int* in_sizes, int n_in,
                              void* d_out, int out_size, void* d_ws, size_t ws_size,
                              hipStream_t stream) {
    const int*   x      = (const int*)d_in[0];
    const int*   ei     = (const int*)d_in[1];
    const int*   batch  = (const int*)d_in[2];
    const float* emb    = (const float*)d_in[3];
    const float* w1_l   = (const float*)d_in[4];
    const float* b1     = (const float*)d_in[5];
    const float* w1_r   = (const float*)d_in[6];
    const float* w2_l   = (const float*)d_in[7];
    const float* b2     = (const float*)d_in[8];
    const float* w2_r   = (const float*)d_in[9];
    const float* w_out  = (const float*)d_in[10];
    const float* b_out  = (const float*)d_in[11];
    float* out = (float*)d_out;

    // workspace layout (floats)
    float* F = (float*)d_ws;
    float* h0    = F;                                 // N*64
    float* mean1 = h0 + (size_t)N_NODES * 64;         // N*64
    float* h1    = mean1 + (size_t)N_NODES * 64;      // N*128
    float* mean2 = h1 + (size_t)N_NODES * 128;        // N*128
    float* h2    = h0;                                // alias N*128: h0+mean1 dead after layer1
    int*   deg   = (int*)(mean2 + (size_t)N_NODES * 128);
    int*   rowptr= deg + N_NODES;                     // N+1
    int*   wp    = rowptr + N_NODES + 1;              // N
    int*   nbr   = wp + N_NODES;                      // E
    int*   bsums = nbr + N_EDGES;                     // 256
    float* wt1r  = (float*)(bsums + 256);             // 128*64
    float* wt1l  = wt1r + 128 * 64;
    float* wt2r  = wt1l + 128 * 64;                   // 128*128
    float* wt2l  = wt2r + 128 * 128;

    const int NB = (N_NODES + 255) / 256;             // 196

    hipMemsetAsync(deg, 0, (size_t)N_NODES * sizeof(int), stream);

    k_embed_hist<<<(N_EDGES + 255) / 256, 256, 0, stream>>>(
        x, emb, ei, h0, deg, w1_r, w1_l, w2_r, w2_l, wt1r, wt1l, wt2r, wt2l);
    k_scanA<<<NB, 256, 0, stream>>>(deg, rowptr, bsums);
    k_scanB<<<1, 256, 0, stream>>>(bsums, NB);
    k_scanC<<<NB, 256, 0, stream>>>(rowptr, wp, bsums);
    k_scatter<<<(N_EDGES + 255) / 256, 256, 0, stream>>>(ei, wp, nbr);

    // layer 1
    k_agg<64><<<(N_NODES + 15) / 16, 256, 0, stream>>>(h0, rowptr, nbr, mean1);
    k_layer<64><<<(N_NODES + 63) / 64, 512, 0, stream>>>(h0, mean1, wt1r, wt1l, b1, h1);

    // layer 2
    k_agg<128><<<(N_NODES + 7) / 8, 256, 0, stream>>>(h1, rowptr, nbr, mean2);
    k_layer<128><<<(N_NODES + 63) / 64, 512, 0, stream>>>(h1, mean2, wt2r, wt2l, b2, h2);

    // pool + head
    k_pool_head<<<N_GRAPHS, 256, 0, stream>>>(h2, batch, w_out, b_out, out);

    (void)in_sizes; (void)n_in; (void)out_size; (void)ws_size;
}

// Round 7
// 369.690 us; speedup vs baseline: 1.4242x; 1.4242x over previous
//
#include <hip/hip_runtime.h>
#include <hip/hip_bf16.h>

#define N_NODES 50000
#define N_EDGES 800000
#define N_GRAPHS 512
#define EMB 64
#define HID 128

// -------------------------------------------- embed gather + degree histogram
__global__ void k_embed_hist(const int* __restrict__ x, const float* __restrict__ emb,
                             const int* __restrict__ ei, float* __restrict__ h0,
                             int* __restrict__ deg) {
    int t = blockIdx.x * 256 + threadIdx.x;
    if (t >= N_EDGES) return;
    int n = t >> 4, c4 = t & 15;
    const float4* e4 = (const float4*)emb;
    ((float4*)h0)[(size_t)n * 16 + c4] = e4[(size_t)x[n] * 16 + c4];
    atomicAdd(&deg[ei[N_EDGES + t]], 1);
}

// ---------------------------------------------------------------- 3-phase scan
__global__ void k_scanA(const int* __restrict__ deg, int* __restrict__ rowptr,
                        int* __restrict__ bsums) {
    __shared__ int s[256];
    int t = threadIdx.x, i = blockIdx.x * 256 + t;
    int v = (i < N_NODES) ? deg[i] : 0;
    s[t] = v; __syncthreads();
    int xv = v;
    for (int off = 1; off < 256; off <<= 1) {
        int y = (t >= off) ? s[t - off] : 0;
        __syncthreads();
        xv += y; s[t] = xv;
        __syncthreads();
    }
    if (i < N_NODES) rowptr[i] = xv - v;
    if (t == 255) bsums[blockIdx.x] = xv;
}

__global__ void k_scanB(int* __restrict__ bsums, int nb) {
    __shared__ int s[256];
    int t = threadIdx.x;
    int v = (t < nb) ? bsums[t] : 0;
    s[t] = v; __syncthreads();
    int xv = v;
    for (int off = 1; off < 256; off <<= 1) {
        int y = (t >= off) ? s[t - off] : 0;
        __syncthreads();
        xv += y; s[t] = xv;
        __syncthreads();
    }
    if (t < nb) bsums[t] = xv - v;
}

__global__ void k_scanC(int* __restrict__ rowptr, int* __restrict__ wp,
                        const int* __restrict__ bsums) {
    int i = blockIdx.x * 256 + threadIdx.x;
    if (i < N_NODES) {
        int v = rowptr[i] + bsums[blockIdx.x];
        rowptr[i] = v;
        wp[i] = v;
    }
    if (i == 0) rowptr[N_NODES] = N_EDGES;
}

// ---------------------------------------------------------------- edge scatter
__global__ void k_scatter(const int* __restrict__ ei, int* __restrict__ wp,
                          int* __restrict__ nbr) {
    int e = blockIdx.x * 256 + threadIdx.x;
    if (e >= N_EDGES) return;
    int s = ei[e], d = ei[N_EDGES + e];
    int pos = atomicAdd(&wp[d], 1);
    nbr[pos] = s;
}

// -------------------------------------------------------- agg device function
// 512-thr block handles 32 (F=64) / 16 (F=128) nodes; 8-deep ILP unroll.
template <int F>
__device__ __forceinline__ void agg_tile(const float* __restrict__ h,
                                         const int* __restrict__ rowptr,
                                         const int* __restrict__ nbr,
                                         float* __restrict__ mean,
                                         int aggIdx, int t) {
    int wl = t >> 6;                 // wave in block 0..7
    int l = t & 63;
    const float4* h4 = (const float4*)h;
    float4* m4 = (float4*)mean;

    int n, c;
    if constexpr (F == 128) { n = aggIdx * 16 + wl * 2 + (l >> 5); c = l & 31; }
    else                    { n = aggIdx * 32 + wl * 4 + (l >> 4); c = l & 15; }
    if (n >= N_NODES) return;
    constexpr int C = F / 4;

    int r0 = rowptr[n], r1 = rowptr[n + 1];
    float inv = 1.0f / (float)max(r1 - r0, 1);

    float4 a[8];
    #pragma unroll
    for (int u = 0; u < 8; ++u) a[u] = make_float4(0.f, 0.f, 0.f, 0.f);

    int i = r0;
    for (; i + 7 < r1; i += 8) {
        int s0 = nbr[i + 0], s1 = nbr[i + 1], s2 = nbr[i + 2], s3 = nbr[i + 3];
        int s4 = nbr[i + 4], s5 = nbr[i + 5], s6 = nbr[i + 6], s7 = nbr[i + 7];
        float4 v0 = h4[(size_t)s0 * C + c];
        float4 v1 = h4[(size_t)s1 * C + c];
        float4 v2 = h4[(size_t)s2 * C + c];
        float4 v3 = h4[(size_t)s3 * C + c];
        float4 v4 = h4[(size_t)s4 * C + c];
        float4 v5 = h4[(size_t)s5 * C + c];
        float4 v6 = h4[(size_t)s6 * C + c];
        float4 v7 = h4[(size_t)s7 * C + c];
        a[0].x += v0.x; a[0].y += v0.y; a[0].z += v0.z; a[0].w += v0.w;
        a[1].x += v1.x; a[1].y += v1.y; a[1].z += v1.z; a[1].w += v1.w;
        a[2].x += v2.x; a[2].y += v2.y; a[2].z += v2.z; a[2].w += v2.w;
        a[3].x += v3.x; a[3].y += v3.y; a[3].z += v3.z; a[3].w += v3.w;
        a[4].x += v4.x; a[4].y += v4.y; a[4].z += v4.z; a[4].w += v4.w;
        a[5].x += v5.x; a[5].y += v5.y; a[5].z += v5.z; a[5].w += v5.w;
        a[6].x += v6.x; a[6].y += v6.y; a[6].z += v6.z; a[6].w += v6.w;
        a[7].x += v7.x; a[7].y += v7.y; a[7].z += v7.z; a[7].w += v7.w;
    }
    for (; i + 3 < r1; i += 4) {
        int s0 = nbr[i + 0], s1 = nbr[i + 1], s2 = nbr[i + 2], s3 = nbr[i + 3];
        float4 v0 = h4[(size_t)s0 * C + c];
        float4 v1 = h4[(size_t)s1 * C + c];
        float4 v2 = h4[(size_t)s2 * C + c];
        float4 v3 = h4[(size_t)s3 * C + c];
        a[0].x += v0.x; a[0].y += v0.y; a[0].z += v0.z; a[0].w += v0.w;
        a[1].x += v1.x; a[1].y += v1.y; a[1].z += v1.z; a[1].w += v1.w;
        a[2].x += v2.x; a[2].y += v2.y; a[2].z += v2.z; a[2].w += v2.w;
        a[3].x += v3.x; a[3].y += v3.y; a[3].z += v3.z; a[3].w += v3.w;
    }
    for (; i < r1; ++i) {
        float4 v = h4[(size_t)nbr[i] * C + c];
        a[0].x += v.x; a[0].y += v.y; a[0].z += v.z; a[0].w += v.w;
    }
    #pragma unroll
    for (int u = 1; u < 8; ++u) {
        a[0].x += a[u].x; a[0].y += a[u].y; a[0].z += a[u].z; a[0].w += a[u].w;
    }
    m4[(size_t)n * C + c] = make_float4(a[0].x * inv, a[0].y * inv,
                                        a[0].z * inv, a[0].w * inv);
}

// ------------------------------------------------------- GEMM device function
// 64-node tile staged in LDS (stride K+2); 8 waves; wave w -> cols [16w,16w+16);
// lane -> node; weights via uniform s_load streams.
// MEAN=false: acc = bias, write raw.  MEAN=true: acc = out[] (RMW), relu, write.
template <int K, bool MEAN>
__device__ __forceinline__ void gemm_tile(const float* __restrict__ hin,
                                          const float* __restrict__ w,
                                          const float* __restrict__ bias,
                                          float* __restrict__ out,
                                          int blk, int t, float* ls) {
    constexpr int LS = K + 2;
    constexpr int C4 = K / 4;
    int base = blk * 64;
    int lane = t & 63;
    int wid = __builtin_amdgcn_readfirstlane(t >> 6);
    int j0 = wid * 16;
    int node = base + lane;
    bool valid = node < N_NODES;

    const float4* h4 = (const float4*)hin;
    for (int idx = t; idx < 64 * C4; idx += 512) {
        int r = idx / C4, c4 = idx % C4;
        float4 v = (base + r < N_NODES) ? h4[(size_t)(base + r) * C4 + c4]
                                        : make_float4(0.f, 0.f, 0.f, 0.f);
        float* dp = &ls[r * LS + c4 * 4];
        dp[0] = v.x; dp[1] = v.y; dp[2] = v.z; dp[3] = v.w;
    }
    __syncthreads();

    float acc[16];
    if constexpr (MEAN) {
        const float4* o4 = (const float4*)out;
        #pragma unroll
        for (int jj = 0; jj < 4; ++jj) {
            float4 v = valid ? o4[(size_t)node * 32 + wid * 4 + jj]
                             : make_float4(0.f, 0.f, 0.f, 0.f);
            acc[jj * 4 + 0] = v.x; acc[jj * 4 + 1] = v.y;
            acc[jj * 4 + 2] = v.z; acc[jj * 4 + 3] = v.w;
        }
    } else {
        #pragma unroll
        for (int j = 0; j < 16; ++j) acc[j] = bias[j0 + j];
    }

    const float* lrow = &ls[lane * LS];
    #pragma unroll 4
    for (int k = 0; k < K; ++k) {
        float hv = lrow[k];
        const float* wk = &w[(size_t)k * 128 + j0];
        #pragma unroll
        for (int j = 0; j < 16; ++j) acc[j] = fmaf(hv, wk[j], acc[j]);
    }

    if (!valid) return;
    float4* o4 = (float4*)out;
    #pragma unroll
    for (int jj = 0; jj < 4; ++jj) {
        float4 v;
        if constexpr (MEAN) {
            v.x = fmaxf(acc[jj * 4 + 0], 0.f);
            v.y = fmaxf(acc[jj * 4 + 1], 0.f);
            v.z = fmaxf(acc[jj * 4 + 2], 0.f);
            v.w = fmaxf(acc[jj * 4 + 3], 0.f);
        } else {
            v.x = acc[jj * 4 + 0]; v.y = acc[jj * 4 + 1];
            v.z = acc[jj * 4 + 2]; v.w = acc[jj * 4 + 3];
        }
        o4[(size_t)node * 32 + wid * 4 + jj] = v;
    }
}

// ------------------------------------------------- fused agg ∥ selfGEMM layers
// blockIdx interleave keeps memory-bound agg waves and VALU-bound GEMM waves
// co-resident on every CU.
__global__ __launch_bounds__(512) void k_fuse1(
    const float* __restrict__ h0, const int* __restrict__ rowptr,
    const int* __restrict__ nbr, float* __restrict__ mean1,
    const float* __restrict__ w1r, const float* __restrict__ b1,
    float* __restrict__ h1) {
    __shared__ float ls[64 * (64 + 2)];
    int b = blockIdx.x;
    if (b % 3 == 2)
        gemm_tile<64, false>(h0, w1r, b1, h1, b / 3, threadIdx.x, ls);
    else
        agg_tile<64>(h0, rowptr, nbr, mean1, (b / 3) * 2 + b % 3, threadIdx.x);
}

__global__ __launch_bounds__(512) void k_fuse2(
    const float* __restrict__ h1, const int* __restrict__ rowptr,
    const int* __restrict__ nbr, float* __restrict__ mean2,
    const float* __restrict__ w2r, const float* __restrict__ b2,
    float* __restrict__ h2) {
    __shared__ float ls[64 * (128 + 2)];
    int b = blockIdx.x;
    if (b % 5 == 4)
        gemm_tile<128, false>(h1, w2r, b2, h2, b / 5, threadIdx.x, ls);
    else
        agg_tile<128>(h1, rowptr, nbr, mean2, (b / 5) * 4 + b % 5, threadIdx.x);
}

// ------------------------------------------------- mean GEMM (in-place RMW)
__global__ __launch_bounds__(512) void k_gemm_mean64(
    const float* __restrict__ mean1, const float* __restrict__ w1l,
    float* __restrict__ h1) {
    __shared__ float ls[64 * (64 + 2)];
    gemm_tile<64, true>(mean1, w1l, nullptr, h1, blockIdx.x, threadIdx.x, ls);
}

__global__ __launch_bounds__(512) void k_gemm_mean128(
    const float* __restrict__ mean2, const float* __restrict__ w2l,
    float* __restrict__ h2) {
    __shared__ float ls[64 * (128 + 2)];
    gemm_tile<128, true>(mean2, w2l, nullptr, h2, blockIdx.x, threadIdx.x, ls);
}

// ---------------------------------------------------------------- pool + head
__global__ void k_pool_head(const float* __restrict__ h2, const int* __restrict__ batch,
                            const float* __restrict__ w_out, const float* __restrict__ b_out,
                            float* __restrict__ out) {
    int g = blockIdx.x;
    int lo = 0, hi = N_NODES;
    while (lo < hi) { int mid = (lo + hi) >> 1; if (batch[mid] < g) lo = mid + 1; else hi = mid; }
    int s = lo;
    lo = s; hi = N_NODES;
    while (lo < hi) { int mid = (lo + hi) >> 1; if (batch[mid] < g + 1) lo = mid + 1; else hi = mid; }
    int e = lo;

    int f = threadIdx.x & 127, half = threadIdx.x >> 7;
    float acc = 0.0f;
    for (int r = s + half; r < e; r += 2) acc += h2[(size_t)r * 128 + f];
    __shared__ float tmp[256];
    tmp[threadIdx.x] = acc;
    __syncthreads();
    if (half == 0) {
        float p = (tmp[f] + tmp[f + 128]) / (float)max(e - s, 1);
        tmp[f]       = p * w_out[f * 2 + 0];
        tmp[f + 128] = p * w_out[f * 2 + 1];
    }
    __syncthreads();
    for (int str = 64; str > 0; str >>= 1) {
        if (threadIdx.x < str) {
            tmp[threadIdx.x] += tmp[threadIdx.x + str];
            tmp[threadIdx.x + 128] += tmp[threadIdx.x + 128 + str];
        }
        __syncthreads();
    }
    if (threadIdx.x == 0) {
        out[(size_t)g * 2 + 0] = tmp[0] + b_out[0];
        out[(size_t)g * 2 + 1] = tmp[128] + b_out[1];
    }
}

// ---------------------------------------------------------------- launch
extern "C" void kernel_launch(void* const* d_in, const int* in_sizes, int n_in,
                              void* d_out, int out_size, void* d_ws, size_t ws_size,
                              hipStream_t stream) {
    const int*   x      = (const int*)d_in[0];
    const int*   ei     = (const int*)d_in[1];
    const int*   batch  = (const int*)d_in[2];
    const float* emb    = (const float*)d_in[3];
    const float* w1_l   = (const float*)d_in[4];
    const float* b1     = (const float*)d_in[5];
    const float* w1_r   = (const float*)d_in[6];
    const float* w2_l   = (const float*)d_in[7];
    const float* b2     = (const float*)d_in[8];
    const float* w2_r   = (const float*)d_in[9];
    const float* w_out  = (const float*)d_in[10];
    const float* b_out  = (const float*)d_in[11];
    float* out = (float*)d_out;

    // workspace layout (floats) — same footprint as R4
    float* F = (float*)d_ws;
    float* h0    = F;                                 // N*64
    float* mean1 = h0 + (size_t)N_NODES * 64;         // N*64
    float* h1    = mean1 + (size_t)N_NODES * 64;      // N*128
    float* mean2 = h1 + (size_t)N_NODES * 128;        // N*128
    float* h2    = h0;                                // alias N*128 over h0+mean1
                                                      // (both dead before k_fuse2 writes h2)
    int*   deg   = (int*)(mean2 + (size_t)N_NODES * 128);
    int*   rowptr= deg + N_NODES;                     // N+1
    int*   wp    = rowptr + N_NODES + 1;              // N
    int*   nbr   = wp + N_NODES;                      // E
    int*   bsums = nbr + N_EDGES;                     // 256

    const int NB = (N_NODES + 255) / 256;             // 196
    const int GB = (N_NODES + 63) / 64;               // 782 GEMM blocks

    hipMemsetAsync(deg, 0, (size_t)N_NODES * sizeof(int), stream);

    k_embed_hist<<<(N_EDGES + 255) / 256, 256, 0, stream>>>(x, emb, ei, h0, deg);
    k_scanA<<<NB, 256, 0, stream>>>(deg, rowptr, bsums);
    k_scanB<<<1, 256, 0, stream>>>(bsums, NB);
    k_scanC<<<NB, 256, 0, stream>>>(rowptr, wp, bsums);
    k_scatter<<<(N_EDGES + 255) / 256, 256, 0, stream>>>(ei, wp, nbr);

    // layer 1: agg64 (1564 blocks) ∥ selfGEMM1 (782) interleaved 2:1
    k_fuse1<<<3 * GB, 512, 0, stream>>>(h0, rowptr, nbr, mean1, w1_r, b1, h1);
    k_gemm_mean64<<<GB, 512, 0, stream>>>(mean1, w1_l, h1);

    // layer 2: agg128 (3128 blocks) ∥ selfGEMM2 (782) interleaved 4:1
    k_fuse2<<<5 * GB, 512, 0, stream>>>(h1, rowptr, nbr, mean2, w2_r, b2, h2);
    k_gemm_mean128<<<GB, 512, 0, stream>>>(mean2, w2_l, h2);

    // pool + head
    k_pool_head<<<N_GRAPHS, 256, 0, stream>>>(h2, batch, w_out, b_out, out);

    (void)in_sizes; (void)n_in; (void)out_size; (void)ws_size;
}